// Round 10
// baseline (57.393 us; speedup 1.0000x reference)
//
#include <hip/hip_runtime.h>
#include <hip/hip_bf16.h>

#define NB 4
#define NT 2048
#define DM 1024
#define DH 64

typedef __attribute__((ext_vector_type(8))) short bf16x8;
typedef __attribute__((ext_vector_type(4))) float f32x4;
typedef unsigned short u16;
typedef unsigned int u32;

static __device__ __forceinline__ u16 f2b(float f) {
    __hip_bfloat16 h = __float2bfloat16(f);
    return __builtin_bit_cast(u16, h);
}
static __device__ __forceinline__ float b2f(u16 h) {
    return __builtin_bit_cast(float, (u32)h << 16);
}
// global -> LDS DMA, 16B per lane. lds ptr must be wave-uniform (HW adds lane*16).
static __device__ __forceinline__ void gld16(const void* g, void* l) {
    __builtin_amdgcn_global_load_lds((const __attribute__((address_space(1))) void*)g,
                                     (__attribute__((address_space(3))) void*)l, 16, 0, 0);
}
#define BAR() __builtin_amdgcn_s_barrier()
#define SBAR() __builtin_amdgcn_sched_barrier(0)

// ---------------------------------------------------------------------------
// Wt[which][d][k] bf16 <- W[k][d] fp32, via LDS transpose. grid (16, 3)
// ---------------------------------------------------------------------------
__global__ __launch_bounds__(256) void wt_conv(
    const float* __restrict__ WQ, const float* __restrict__ WK,
    const float* __restrict__ WV, u16* __restrict__ wt)
{
    __shared__ u16 tl[64][68];
    const int which = blockIdx.y, kt = blockIdx.x;
    const float* W = (which == 0) ? WQ : (which == 1) ? WK : WV;
    #pragma unroll
    for (int i = 0; i < 4; ++i) {
        int r = (threadIdx.x >> 4) + i * 16;         // k-local
        int c = (threadIdx.x & 15) * 4;              // d
        float4 v = *(const float4*)&W[(size_t)(kt * 64 + r) * DH + c];
        tl[r][c] = f2b(v.x); tl[r][c + 1] = f2b(v.y);
        tl[r][c + 2] = f2b(v.z); tl[r][c + 3] = f2b(v.w);
    }
    __syncthreads();
    int d = threadIdx.x >> 2, kc = (threadIdx.x & 3) * 16;
    u16 buf[16];
    #pragma unroll
    for (int j = 0; j < 16; ++j) buf[j] = tl[kc + j][d];
    u16* dst = wt + which * 65536 + d * 1024 + kt * 64 + kc;
    *(uint4*)dst = *(uint4*)&buf[0];
    *(uint4*)(dst + 8) = *(uint4*)&buf[8];
}

// ---------------------------------------------------------------------------
// QKV GEMM (round-6 structure, unchanged). grid (128, 3).
// 2-buffer pipeline, counted vmcnt (6 DMA/wave/stage).
// ---------------------------------------------------------------------------
__global__ __launch_bounds__(256) void qkv_gemm(
    const float* __restrict__ x, const u16* __restrict__ wt,
    u16* __restrict__ Qb, u16* __restrict__ Kb, u16* __restrict__ Vt)
{
    __shared__ float xs[2][4096];     // 2 x 16 KB fp32, swizzle ^((r&7)<<5)
    __shared__ u16 wsm[2][4096];      // 2 x  8 KB bf16, swizzle ^((r&7)<<4)
    const int tid = threadIdx.x, lane = tid & 63, w = tid >> 6;
    const int l15 = lane & 15, g = lane >> 4;
    const int row0 = blockIdx.x * 64;
    const int which = blockIdx.y;
    const u16* Wg = wt + which * 65536;

    auto stage = [&](int kt, int bi) {
        #pragma unroll
        for (int i = 0; i < 4; ++i) {
            u32 D = (u32)(w * 4096 + i * 1024 + lane * 16);
            u32 r = D >> 8, c = D & 255;
            u32 cs = c ^ ((r & 7) << 5);
            gld16(x + (size_t)(row0 + r) * DM + kt * 64 + (cs >> 2),
                  (char*)&xs[bi][0] + w * 4096 + i * 1024);
        }
        #pragma unroll
        for (int i = 0; i < 2; ++i) {
            u32 D = (u32)(w * 2048 + i * 1024 + lane * 16);
            u32 r = D >> 7, c = D & 127;
            u32 cs = c ^ ((r & 7) << 4);
            gld16(Wg + (size_t)r * 1024 + kt * 64 + (cs >> 1),
                  (char*)&wsm[bi][0] + w * 2048 + i * 1024);
        }
    };

    f32x4 acc[4];
    #pragma unroll
    for (int i = 0; i < 4; ++i) acc[i] = {0.f, 0.f, 0.f, 0.f};

    stage(0, 0);

    const int arow = w * 16 + l15;
    #pragma unroll
    for (int kt = 0; kt < 16; ++kt) {
        if (kt < 15) {
            stage(kt + 1, (kt + 1) & 1);
            asm volatile("s_waitcnt vmcnt(6)" ::: "memory");
        } else {
            asm volatile("s_waitcnt vmcnt(0)" ::: "memory");
        }
        BAR();                                    // publish buf[kt&1]
        SBAR();
        const char* xb = (const char*)&xs[kt & 1][0];
        const char* wb = (const char*)&wsm[kt & 1][0];
        #pragma unroll
        for (int ks = 0; ks < 2; ++ks) {
            u32 abase = (u32)(arow * 256 + ks * 128 + g * 32);
            f32x4 a0 = *(const f32x4*)(xb + (abase ^ ((arow & 7) << 5)));
            f32x4 a1 = *(const f32x4*)(xb + ((abase + 16) ^ ((arow & 7) << 5)));
            bf16x8 afrag;
            #pragma unroll
            for (int e = 0; e < 4; ++e) afrag[e] = (short)f2b(a0[e]);
            #pragma unroll
            for (int e = 0; e < 4; ++e) afrag[4 + e] = (short)f2b(a1[e]);
            __builtin_amdgcn_s_setprio(1);
            #pragma unroll
            for (int nt = 0; nt < 4; ++nt) {
                int brow = nt * 16 + l15;
                u32 bb = (u32)(brow * 128 + ks * 64 + g * 16);
                bf16x8 bfrag = *(const bf16x8*)(wb + (bb ^ ((brow & 7) << 4)));
                acc[nt] = __builtin_amdgcn_mfma_f32_16x16x32_bf16(afrag, bfrag, acc[nt], 0, 0, 0);
            }
            __builtin_amdgcn_s_setprio(0);
        }
        BAR();                                    // release buf[kt&1]
    }
    // epilogue: C col=l15(+16nt), row=g*4+r
    #pragma unroll
    for (int nt = 0; nt < 4; ++nt) {
        int dcol = nt * 16 + l15;
        #pragma unroll
        for (int r = 0; r < 4; ++r) {
            int row = row0 + w * 16 + g * 4 + r;
            float v = acc[nt][r];
            if (which == 0)      Qb[(size_t)row * DH + dcol] = f2b(v * 0.125f);
            else if (which == 1) Kb[(size_t)row * DH + dcol] = f2b(v);
            else { int bb2 = row >> 11, t = row & 2047;
                   Vt[(size_t)bb2 * DH * NT + (size_t)dcol * NT + t] = f2b(v); }
        }
    }
}

// ---------------------------------------------------------------------------
// Flash attention, single kernel, NO merge pass. QBLK=16, grid (128, NB) =
// 512 blocks. The 4 waves of a block are 4 INDEPENDENT KV streams
// (t = w, w+4, ...): no staging LDS, no in-loop barriers; K/V fragments
// direct from global (Kb+Vt = 2MB, L2-resident; pattern verified in R7).
// Swapped operands: St = mfma(K,Q) -> lane-local q-row scores, softmax
// in-register + xor16/xor32; PV = mfma(Vt,P^T) -> O^T in regs.
// End: one __syncthreads, 4-way m/l/O combine in LDS, fp32 out direct.
// ---------------------------------------------------------------------------
__global__ __launch_bounds__(256) void attn2(
    const u16* __restrict__ Qb, const u16* __restrict__ Kb,
    const u16* __restrict__ Vt, float* __restrict__ out)
{
    __shared__ f32x4 p_lds[4][128];       // per-wave P repack (2 KB each)
    __shared__ float o_lds[4][64][17];    // O^T partials, padded (17.4 KB)
    __shared__ float ml_lds[4][2][16];    // m, l per stream per q

    const int tid = threadIdx.x, lane = tid & 63, w = tid >> 6;
    const int l15 = lane & 15, g = lane >> 4;
    const int b = blockIdx.y;
    const int qb16 = blockIdx.x;           // 16-row q block
    const int q0 = qb16 * 16;
    const int T = (qb16 >> 2) + 1;         // KV tiles of 64
    const int tD = T - 1;                  // diagonal tile
    const int moff = (qb16 & 3) * 16;      // q0 - tD*64

    const u16* Qg = Qb + ((size_t)b * NT + q0) * DH;
    const u16* Kg = Kb + (size_t)b * NT * DH + (size_t)l15 * DH + g * 8;
    const u16* Vg = Vt + (size_t)b * DH * NT + (size_t)l15 * NT + g * 8;

    // Q fragment (B-operand): col=l15 -> q = q0+l15, k = ks*32+g*8+e over d
    bf16x8 qf[2];
    qf[0] = *(const bf16x8*)(Qg + l15 * DH + g * 8);
    qf[1] = *(const bf16x8*)(Qg + l15 * DH + 32 + g * 8);

    float m_run = -INFINITY, l_run = 0.f;
    f32x4 oacc[4];                         // O^T: d = nt*16+g*4+r, q = q0+l15
    #pragma unroll
    for (int nt = 0; nt < 4; ++nt) oacc[nt] = {0.f, 0.f, 0.f, 0.f};

    char* pw = (char*)&p_lds[w][0];
    const int swz = (l15 & 7) << 4;

    for (int t = w; t < T; t += 4) {
        const int j0 = t * 64;
        // ---- K, V fragments direct from global ----
        const u16* kp = Kg + (size_t)j0 * DH;     // row j = j0 + nt*16 + l15
        const u16* vp = Vg + j0;                  // row d = nt*16 + l15
        bf16x8 kf[8], vf[8];
        #pragma unroll
        for (int nt = 0; nt < 4; ++nt) {
            kf[nt * 2]     = *(const bf16x8*)(kp + nt * 16 * DH);
            kf[nt * 2 + 1] = *(const bf16x8*)(kp + nt * 16 * DH + 32);
        }
        #pragma unroll
        for (int nt = 0; nt < 4; ++nt) {
            vf[nt * 2]     = *(const bf16x8*)(vp + nt * 16 * NT);
            vf[nt * 2 + 1] = *(const bf16x8*)(vp + nt * 16 * NT + 32);
        }

        // ---- QK^T swapped: sacc[nt][r] = S[j0 + nt*16+g*4+r][q0 + l15] ----
        f32x4 sacc[4];
        #pragma unroll
        for (int nt = 0; nt < 4; ++nt) sacc[nt] = {0.f, 0.f, 0.f, 0.f};
        __builtin_amdgcn_s_setprio(1);
        #pragma unroll
        for (int ks = 0; ks < 2; ++ks)
            #pragma unroll
            for (int nt = 0; nt < 4; ++nt)
                sacc[nt] = __builtin_amdgcn_mfma_f32_16x16x32_bf16(
                    kf[nt * 2 + ks], qf[ks], sacc[nt], 0, 0, 0);
        __builtin_amdgcn_s_setprio(0);
        if (t == tD) {  // causal mask: j0+jj > q0+l15  <=>  jj > moff+l15
            #pragma unroll
            for (int nt = 0; nt < 4; ++nt)
                #pragma unroll
                for (int r = 0; r < 4; ++r)
                    if (nt * 16 + g * 4 + r > moff + l15) sacc[nt][r] = -1e30f;
        }
        // ---- online softmax: per-lane 16 values + xor16/xor32 ----
        float mx = -INFINITY;
        #pragma unroll
        for (int nt = 0; nt < 4; ++nt) {
            float a = fmaxf(fmaxf(sacc[nt][0], sacc[nt][1]),
                            fmaxf(sacc[nt][2], sacc[nt][3]));
            mx = fmaxf(mx, a);
        }
        mx = fmaxf(mx, __shfl_xor(mx, 16));
        mx = fmaxf(mx, __shfl_xor(mx, 32));
        const float m_new = fmaxf(m_run, mx);
        const float alpha = __expf(m_run - m_new);
        float p[4][4];
        float ps = 0.f;
        #pragma unroll
        for (int nt = 0; nt < 4; ++nt)
            #pragma unroll
            for (int r = 0; r < 4; ++r) {
                float pv = __expf(sacc[nt][r] - m_new);
                p[nt][r] = pv; ps += pv;
            }
        ps += __shfl_xor(ps, 16);
        ps += __shfl_xor(ps, 32);
        l_run = l_run * alpha + ps;
        m_run = m_new;
        #pragma unroll
        for (int nt = 0; nt < 4; ++nt)
            #pragma unroll
            for (int r = 0; r < 4; ++r) oacc[nt][r] *= alpha;

        // ---- P^T repack via per-wave LDS (same-wave, no barrier) ----
        #pragma unroll
        for (int nt = 0; nt < 4; ++nt) {
            uint2 pk;
            pk.x = (u32)f2b(p[nt][0]) | ((u32)f2b(p[nt][1]) << 16);
            pk.y = (u32)f2b(p[nt][2]) | ((u32)f2b(p[nt][3]) << 16);
            u32 a = (u32)((l15 * 128 + nt * 32 + g * 8) ^ swz);
            *(uint2*)(pw + a) = pk;
        }
        bf16x8 pb_[2];
        #pragma unroll
        for (int ks = 0; ks < 2; ++ks)
            pb_[ks] = *(const bf16x8*)(pw + ((u32)(l15 * 128 + ks * 64 + g * 16) ^ swz));

        // ---- PV swapped: oacc[nt] += Vt[d][j] @ P^T[j][q] ----
        __builtin_amdgcn_s_setprio(1);
        #pragma unroll
        for (int ks = 0; ks < 2; ++ks)
            #pragma unroll
            for (int nt = 0; nt < 4; ++nt)
                oacc[nt] = __builtin_amdgcn_mfma_f32_16x16x32_bf16(
                    vf[nt * 2 + ks], pb_[ks], oacc[nt], 0, 0, 0);
        __builtin_amdgcn_s_setprio(0);
    }

    // ---- publish per-stream partials ----
    if (g == 0) { ml_lds[w][0][l15] = m_run; ml_lds[w][1][l15] = l_run; }
    #pragma unroll
    for (int nt = 0; nt < 4; ++nt)
        #pragma unroll
        for (int r = 0; r < 4; ++r)
            o_lds[w][nt * 16 + g * 4 + r][l15] = oacc[nt][r];
    __syncthreads();

    // ---- 4-way combine, final normalized fp32 output ----
    const int q = tid >> 4, d0 = (tid & 15) * 4;
    float ms[4];
    #pragma unroll
    for (int s = 0; s < 4; ++s) ms[s] = ml_lds[s][0][q];
    float mstar = fmaxf(fmaxf(ms[0], ms[1]), fmaxf(ms[2], ms[3]));
    float wgt[4];
    float L = 0.f;
    #pragma unroll
    for (int s = 0; s < 4; ++s) {
        wgt[s] = __expf(ms[s] - mstar);
        L += wgt[s] * ml_lds[s][1][q];
    }
    const float inv = 1.f / L;
    float4 o;
    #pragma unroll
    for (int j = 0; j < 4; ++j) {
        float v = 0.f;
        #pragma unroll
        for (int s = 0; s < 4; ++s) v += wgt[s] * o_lds[s][d0 + j][q];
        (&o.x)[j] = v * inv;
    }
    *(float4*)&out[((size_t)b * NT + q0 + q) * DH + d0] = o;
}

extern "C" void kernel_launch(void* const* d_in, const int* in_sizes, int n_in,
                              void* d_out, int out_size, void* d_ws, size_t ws_size,
                              hipStream_t stream) {
    const float* x  = (const float*)d_in[0];
    const float* WQ = (const float*)d_in[1];
    const float* WK = (const float*)d_in[2];
    const float* WV = (const float*)d_in[3];
    float* out = (float*)d_out;

    char* ws = (char*)d_ws;
    u16* Qb = (u16*)ws;                       // 1 MB
    u16* Kb = (u16*)(ws + 1048576);           // 1 MB
    u16* Vt = (u16*)(ws + 2097152);           // 1 MB
    u16* Wt = (u16*)(ws + 3145728);           // 384 KB

    wt_conv<<<dim3(16, 3), 256, 0, stream>>>(WQ, WK, WV, Wt);
    qkv_gemm<<<dim3(128, 3), 256, 0, stream>>>(x, Wt, Qb, Kb, Vt);
    attn2<<<dim3(NT / 16, NB), 256, 0, stream>>>(Qb, Kb, Vt, out);
}